// Round 17
// baseline (1351.267 us; speedup 1.0000x reference)
//
#include <hip/hip_runtime.h>
#include <hip/hip_fp8.h>
#include <hip/hip_bf16.h>

// Problem constants: M=8192, H=4096 (=K=N), GROUP=128.
#define MDIM 8192
#define HDIM 4096
#define NKT 64  // K tiles of 64

typedef float f32x4 __attribute__((ext_vector_type(4)));
typedef short bf16x8 __attribute__((ext_vector_type(8)));
typedef unsigned short u16x4 __attribute__((ext_vector_type(4)));

__device__ inline void gload_lds16(const void* g, void* l) {
  __builtin_amdgcn_global_load_lds(
      (const __attribute__((address_space(1))) void*)g,
      (__attribute__((address_space(3))) void*)l, 16, 0, 0);
}

__device__ inline unsigned short f2bf(float f) {
  __hip_bfloat16 h = __float2bfloat16(f);
  return *reinterpret_cast<unsigned short*>(&h);
}

// ---------------------------------------------------------------------------
// Kernel 1: y = silu(gate)*up; per-(1,128) fp8 group quant; emit y_dq as bf16.
// ---------------------------------------------------------------------------
__global__ __launch_bounds__(256) void silu_quant_kernel(
    const float* __restrict__ x, unsigned short* __restrict__ yb) {
  const int m = blockIdx.x;
  const int t = threadIdx.x;
  const int g = t >> 3;   // group 0..31
  const int i = t & 7;    // lane-in-group
  const float* xr = x + (size_t)m * (2 * HDIM);

  float v[16];
  float amax = 0.f;
#pragma unroll
  for (int j = 0; j < 4; ++j) {
    const int off = g * 128 + j * 32 + i * 4;
    f32x4 gate = *(const f32x4*)(xr + off);
    f32x4 up = *(const f32x4*)(xr + HDIM + off);
#pragma unroll
    for (int c = 0; c < 4; ++c) {
      float gg = gate[c];
      float s = gg / (1.f + expf(-gg));
      float val = s * up[c];
      v[j * 4 + c] = val;
      amax = fmaxf(amax, fabsf(val));
    }
  }
#pragma unroll
  for (int d = 1; d < 8; d <<= 1) amax = fmaxf(amax, __shfl_xor(amax, d, 64));
  const float scale = fmaxf(amax, 1e-12f) / 448.0f;

#pragma unroll
  for (int j = 0; j < 4; ++j) {
    u16x4 pk;
#pragma unroll
    for (int c = 0; c < 4; ++c) {
      __hip_fp8_e4m3 qv(v[j * 4 + c] / scale);  // RNE onto e4m3fn grid
      pk[c] = f2bf((float)qv * scale);          // dequantized, to bf16
    }
    *(u16x4*)(yb + (size_t)m * HDIM + g * 128 + j * 32 + i * 4) = pk;
  }
}

// ---------------------------------------------------------------------------
// Kernel 2: wt[n][k] = bf16( w_q[k][n] * wscale[k/128][n/128] )  (transposed)
// ---------------------------------------------------------------------------
__global__ __launch_bounds__(256) void wconv_kernel(
    const float* __restrict__ w, const float* __restrict__ wsc,
    unsigned short* __restrict__ wt) {
  __shared__ unsigned short tile[64][66];
  const int t = threadIdx.x;
  const int n0 = (blockIdx.x & 63) * 64;
  const int k0 = (blockIdx.x >> 6) * 64;
  const float ws = wsc[(k0 >> 7) * 32 + (n0 >> 7)];
  {
    const int r = t >> 4;
    const int c4 = (t & 15) << 2;
#pragma unroll
    for (int j = 0; j < 4; ++j) {
      const int kr = r + j * 16;
      f32x4 vv = *(const f32x4*)(w + (size_t)(k0 + kr) * HDIM + n0 + c4);
#pragma unroll
      for (int c = 0; c < 4; ++c) tile[kr][c4 + c] = f2bf(vv[c] * ws);
    }
  }
  __syncthreads();
  {
    const int n = t >> 4;
    const int k4 = (t & 15) << 2;
#pragma unroll
    for (int j = 0; j < 4; ++j) {
      const int nn = n + j * 16;
      u16x4 pk;
#pragma unroll
      for (int c = 0; c < 4; ++c) pk[c] = tile[k4 + c][nn];
      *(u16x4*)(wt + (size_t)(n0 + nn) * HDIM + k0 + k4) = pk;
    }
  }
}

// ---------------------------------------------------------------------------
// Kernel 3: bf16 GEMM, 256x256 tile, BK=64, 8 waves (2Mx4N, 128x64 each).
// DEEP-PREFETCH m201-style schedule with asymmetric buffer depths:
//   Abuf: 3 x 32KB (depth-3), Bbuf: 2 x 32KB (depth-2) = 160KB LDS (HW max).
// Per iter j (4 phases, each {RD quadrant, stage 1 unit, SBAR, LGKM0,
// prio1 16xMFMA prio0, SBAR}):
//   P1: RD q(0,0)[12 b128]; stage B-lo(T(j+1)) -> Bbuf[(j+1)%2]
//   P2: RD q(1,0)[8];       stage B-hi(T(j+1))
//   P3: RD q(1,1)[4];       stage A-lo(T(j+2)) -> Abuf[(j+2)%3]
//   P4: (reg MFMA q(0,1));  stage A-hi(T(j+2)); VMW(4); SBAR; MFMA; SBAR
// VMW(4) FIFO ledger at P4: outstanding = A(T(j+1))[4, issued j-1 P3/P4] +
// B(T(j+1))[4, issued j P1/P2] + A(T(j+2))[4, issued j P3/P4] = 12; waits
// oldest 8 = ALL of T(j+1); slack >= 2 phases (~2200 cyc) > HBM latency.
// Buffer safety: B write target Bbuf[(j+1)%2] held T(j-1), reads drained by
// iter j-1's P3 LGKM0 + barriers; A write target Abuf[(j+2)%3] held T(j-1),
// same argument. All units of T(j+1) confirmed before ANY iter-j+1 read.
// LDS: row-major 128B rows, stored 16B-chunk = chunk ^ (row&7); linear dest
// + pre-swizzled global source + swizzled ds_read (rule 21). Conflict-free
// (r6-r13: SQ_LDS_BANK_CONFLICT = 0).
// ---------------------------------------------------------------------------
#define SCHED0 __builtin_amdgcn_sched_barrier(0)
#define SBAR do { SCHED0; __builtin_amdgcn_s_barrier(); SCHED0; } while (0)
#define VMW(n) asm volatile("s_waitcnt vmcnt(" #n ")" ::: "memory")
#define LGKM0 asm volatile("s_waitcnt lgkmcnt(0)" ::: "memory")
#define PRIO1 __builtin_amdgcn_s_setprio(1)
#define PRIO0 __builtin_amdgcn_s_setprio(0)

// stage half-tile unit: h=0 rows 0-127, h=1 rows 128-255 (of the 256-row tile)
#define STAGE_A(bi, kt, h) do {                                              \
    const __hip_bfloat16* g =                                                \
        A + (size_t)(m0 + (h) * 128 + r0) * HDIM + (kt) * 64 + cst * 8;      \
    unsigned char* l = Asb + (bi) * 32768 + (h) * 16384 + t * 16;            \
    gload_lds16(g, l); gload_lds16(g + (size_t)64 * HDIM, l + 8192);         \
  } while (0)

#define STAGE_B(bi, kt, h) do {                                              \
    const __hip_bfloat16* g =                                                \
        B + (size_t)(n0 + (h) * 128 + r0) * HDIM + (kt) * 64 + cst * 8;      \
    unsigned char* l = Bsb + (bi) * 32768 + (h) * 16384 + t * 16;            \
    gload_lds16(g, l); gload_lds16(g + (size_t)64 * HDIM, l + 8192);         \
  } while (0)

#define RD_A(Ab, mh, dst) do { _Pragma("unroll") for (int mi = 0; mi < 4; ++mi) { \
    const int row = wm * 128 + (mh) * 64 + mi * 16 + lrow;                        \
    _Pragma("unroll") for (int kk = 0; kk < 2; ++kk)                              \
      dst[mi][kk] = *(const bf16x8*)((Ab) + row * 128 + (((kk * 4 + lhi) ^ rx) * 16)); \
  } } while (0)

#define RD_B(Bb, nh, dst) do { _Pragma("unroll") for (int ni = 0; ni < 2; ++ni) { \
    const int row = wn * 64 + (nh) * 32 + ni * 16 + lrow;                         \
    _Pragma("unroll") for (int kk = 0; kk < 2; ++kk)                              \
      dst[ni][kk] = *(const bf16x8*)((Bb) + row * 128 + (((kk * 4 + lhi) ^ rx) * 16)); \
  } } while (0)

#define MFMA16(AF, BF, MB, NB) do { _Pragma("unroll") for (int kk = 0; kk < 2; ++kk) \
    _Pragma("unroll") for (int mi = 0; mi < 4; ++mi)                                 \
      _Pragma("unroll") for (int ni = 0; ni < 2; ++ni)                               \
        acc[(MB) + mi][(NB) + ni] = __builtin_amdgcn_mfma_f32_16x16x32_bf16(         \
            AF[mi][kk], BF[ni][kk], acc[(MB) + mi][(NB) + ni], 0, 0, 0);             \
  } while (0)

#define ITER(j, ar, br, aw, bw, SHB, SHA, VMSTMT) do {                        \
    const unsigned char* Ac = Asb + (ar) * 32768;                             \
    const unsigned char* Bc = Bsb + (br) * 32768;                             \
    /* P1: q(0,0); stage B-lo(T(j+1)) */                                      \
    RD_B(Bc, 0, bfr0); RD_A(Ac, 0, afr0);                                     \
    if (SHB) STAGE_B(bw, (j) + 1, 0);                                         \
    SBAR; LGKM0; SCHED0;                                                      \
    PRIO1; MFMA16(afr0, bfr0, 0, 0); PRIO0;                                   \
    SBAR;                                                                     \
    /* P2: q(1,0); stage B-hi(T(j+1)) */                                      \
    RD_A(Ac, 1, afr1);                                                        \
    if (SHB) STAGE_B(bw, (j) + 1, 1);                                         \
    SBAR; LGKM0; SCHED0;                                                      \
    PRIO1; MFMA16(afr1, bfr0, 4, 0); PRIO0;                                   \
    SBAR;                                                                     \
    /* P3: q(1,1); stage A-lo(T(j+2)) */                                      \
    RD_B(Bc, 1, bfr1);                                                        \
    if (SHA) STAGE_A(aw, (j) + 2, 0);                                         \
    SBAR; LGKM0; SCHED0;                                                      \
    PRIO1; MFMA16(afr1, bfr1, 4, 2); PRIO0;                                   \
    SBAR;                                                                     \
    /* P4: q(0,1) from regs; stage A-hi(T(j+2)); counted wait */              \
    if (SHA) STAGE_A(aw, (j) + 2, 1);                                         \
    VMSTMT;                                                                   \
    SBAR;                                                                     \
    PRIO1; MFMA16(afr0, bfr1, 0, 2); PRIO0;                                   \
    SBAR;                                                                     \
  } while (0)

__global__ __launch_bounds__(512, 1) void gemm_bf16_kernel(
    const __hip_bfloat16* __restrict__ A,   // y_dq [8192][4096]
    const __hip_bfloat16* __restrict__ B,   // w_dq^T [4096][4096] (n-major)
    float* __restrict__ out) {              // [8192][4096]
  __shared__ __align__(16) unsigned char Asb[3 * 32768];  // 96 KB, depth-3
  __shared__ __align__(16) unsigned char Bsb[2 * 32768];  // 64 KB, depth-2

  // XCD-aware swizzle: grid 512 = 32m x 16n tiles; XCD x gets an 8x8 sub-grid.
  const int bid = blockIdx.x;
  const int x = bid & 7, sub = bid >> 3;
  const int mtile = (x >> 1) * 8 + (sub & 7);
  const int ntile = (x & 1) * 8 + (sub >> 3);
  const int m0 = mtile * 256, n0 = ntile * 256;

  const int t = threadIdx.x;
  const int l = t & 63, wid = t >> 6;
  const int wm = wid >> 2, wn = wid & 3;    // 2x4 waves, 128x64 each
  const int lrow = l & 15, lhi = l >> 4;
  const int rx = lrow & 7;

  const int r0 = t >> 3;                    // staging row (0..63)
  const int cst = (t & 7) ^ (r0 & 7);       // pre-swizzled source chunk

  f32x4 acc[8][4];
#pragma unroll
  for (int a = 0; a < 8; ++a)
#pragma unroll
    for (int b = 0; b < 4; ++b) acc[a][b] = (f32x4){0.f, 0.f, 0.f, 0.f};
  bf16x8 afr0[4][2], afr1[4][2], bfr0[2][2], bfr1[2][2];

  // prologue: A(T0)->Abuf0, B(T0)->Bbuf0, A(T1)->Abuf1 (12 loads);
  // VMW(4) confirms T0's 8, leaves A(T1) flying  (iter-0 entry invariant).
  STAGE_A(0, 0, 0); STAGE_A(0, 0, 1);
  STAGE_B(0, 0, 0); STAGE_B(0, 0, 1);
  STAGE_A(1, 1, 0); STAGE_A(1, 1, 1);
  VMW(4);
  SBAR;

  int ar = 0, br = 0;
  for (int j = 0; j < NKT; ++j) {
    const int aw = (ar >= 1) ? ar - 1 : 2;  // (ar+2)%3
    const int bw = br ^ 1;
    if (j <= NKT - 3) {
      ITER(j, ar, br, aw, bw, 1, (j <= NKT - 3) && (j + 2 < NKT), VMW(4));
    } else if (j == NKT - 2) {
      ITER(j, ar, br, aw, bw, 1, 0, VMW(0));  // drain: T(NKT-1) fully landed
    } else {
      ITER(j, ar, br, aw, bw, 0, 0, (void)0);
    }
    ar = (ar >= 2) ? 0 : ar + 1;
    br ^= 1;
  }

  // epilogue: C row = lhi*4+r (m), col = lrow (n)
#pragma unroll
  for (int mi = 0; mi < 8; ++mi)
#pragma unroll
    for (int r = 0; r < 4; ++r) {
      const int grow = m0 + wm * 128 + mi * 16 + lhi * 4 + r;
      float* orow = out + (size_t)grow * HDIM + n0 + wn * 64 + lrow;
#pragma unroll
      for (int ni = 0; ni < 4; ++ni) orow[ni * 16] = acc[mi][ni][r];
    }
}

// ---------------------------------------------------------------------------
extern "C" void kernel_launch(void* const* d_in, const int* in_sizes, int n_in,
                              void* d_out, int out_size, void* d_ws, size_t ws_size,
                              hipStream_t stream) {
  const float* x = (const float*)d_in[0];    // [8192][8192]
  const float* wq = (const float*)d_in[1];   // [4096][4096]
  const float* wsc = (const float*)d_in[2];  // [32][32]
  float* out = (float*)d_out;                // [8192][4096]

  unsigned short* yb = (unsigned short*)d_ws;                   // 64 MiB bf16 y_dq
  unsigned short* wt = yb + (size_t)MDIM * HDIM;                // 32 MiB bf16 w_dq^T

  silu_quant_kernel<<<MDIM, 256, 0, stream>>>(x, yb);
  wconv_kernel<<<(HDIM / 64) * (HDIM / 64), 256, 0, stream>>>(wq, wsc, wt);
  gemm_bf16_kernel<<<(MDIM / 256) * (HDIM / 256), 512, 0, stream>>>(
      (const __hip_bfloat16*)yb, (const __hip_bfloat16*)wt, out);
}

// Round 18
// 334.411 us; speedup vs baseline: 4.0407x; 4.0407x over previous
//
#include <hip/hip_runtime.h>
#include <hip/hip_fp8.h>
#include <hip/hip_bf16.h>

// Problem constants: M=8192, H=4096 (=K=N), GROUP=128.
#define MDIM 8192
#define HDIM 4096
#define NKT 64  // K tiles of 64

typedef float f32x4 __attribute__((ext_vector_type(4)));
typedef float f32x16 __attribute__((ext_vector_type(16)));
typedef short bf16x8 __attribute__((ext_vector_type(8)));
typedef unsigned short u16x4 __attribute__((ext_vector_type(4)));

__device__ inline void gload_lds16(const void* g, void* l) {
  __builtin_amdgcn_global_load_lds(
      (const __attribute__((address_space(1))) void*)g,
      (__attribute__((address_space(3))) void*)l, 16, 0, 0);
}

__device__ inline unsigned short f2bf(float f) {
  __hip_bfloat16 h = __float2bfloat16(f);
  return *reinterpret_cast<unsigned short*>(&h);
}

// ---------------------------------------------------------------------------
// Kernel 1: y = silu(gate)*up; per-(1,128) fp8 group quant; emit y_dq as bf16.
// ---------------------------------------------------------------------------
__global__ __launch_bounds__(256) void silu_quant_kernel(
    const float* __restrict__ x, unsigned short* __restrict__ yb) {
  const int m = blockIdx.x;
  const int t = threadIdx.x;
  const int g = t >> 3;   // group 0..31
  const int i = t & 7;    // lane-in-group
  const float* xr = x + (size_t)m * (2 * HDIM);

  float v[16];
  float amax = 0.f;
#pragma unroll
  for (int j = 0; j < 4; ++j) {
    const int off = g * 128 + j * 32 + i * 4;
    f32x4 gate = *(const f32x4*)(xr + off);
    f32x4 up = *(const f32x4*)(xr + HDIM + off);
#pragma unroll
    for (int c = 0; c < 4; ++c) {
      float gg = gate[c];
      float s = gg / (1.f + expf(-gg));
      float val = s * up[c];
      v[j * 4 + c] = val;
      amax = fmaxf(amax, fabsf(val));
    }
  }
#pragma unroll
  for (int d = 1; d < 8; d <<= 1) amax = fmaxf(amax, __shfl_xor(amax, d, 64));
  const float scale = fmaxf(amax, 1e-12f) / 448.0f;

#pragma unroll
  for (int j = 0; j < 4; ++j) {
    u16x4 pk;
#pragma unroll
    for (int c = 0; c < 4; ++c) {
      __hip_fp8_e4m3 qv(v[j * 4 + c] / scale);  // RNE onto e4m3fn grid
      pk[c] = f2bf((float)qv * scale);          // dequantized, to bf16
    }
    *(u16x4*)(yb + (size_t)m * HDIM + g * 128 + j * 32 + i * 4) = pk;
  }
}

// ---------------------------------------------------------------------------
// Kernel 2: wt[n][k] = bf16( w_q[k][n] * wscale[k/128][n/128] )  (transposed)
// ---------------------------------------------------------------------------
__global__ __launch_bounds__(256) void wconv_kernel(
    const float* __restrict__ w, const float* __restrict__ wsc,
    unsigned short* __restrict__ wt) {
  __shared__ unsigned short tile[64][66];
  const int t = threadIdx.x;
  const int n0 = (blockIdx.x & 63) * 64;
  const int k0 = (blockIdx.x >> 6) * 64;
  const float ws = wsc[(k0 >> 7) * 32 + (n0 >> 7)];
  {
    const int r = t >> 4;
    const int c4 = (t & 15) << 2;
#pragma unroll
    for (int j = 0; j < 4; ++j) {
      const int kr = r + j * 16;
      f32x4 vv = *(const f32x4*)(w + (size_t)(k0 + kr) * HDIM + n0 + c4);
#pragma unroll
      for (int c = 0; c < 4; ++c) tile[kr][c4 + c] = f2bf(vv[c] * ws);
    }
  }
  __syncthreads();
  {
    const int n = t >> 4;
    const int k4 = (t & 15) << 2;
#pragma unroll
    for (int j = 0; j < 4; ++j) {
      const int nn = n + j * 16;
      u16x4 pk;
#pragma unroll
      for (int c = 0; c < 4; ++c) pk[c] = tile[k4 + c][nn];
      *(u16x4*)(wt + (size_t)(n0 + nn) * HDIM + k0 + k4) = pk;
    }
  }
}

// ---------------------------------------------------------------------------
// Kernel 3: bf16 GEMM, 256x256 tile, BK=64, 8 waves (2Mx4N, 128x64 each),
// r8's EXACT sync skeleton/ledger, but 32x32x16 MFMA (2382 vs 2075 TF
// ceiling; 8.07 cyc / 32 KFLOP vs 4.85 / 16 KFLOP => MFMA pipe -17%).
// Per wave: 4m x 2n tiles of 32x32; per K-tile 4 ksteps of 16 -> 32 MFMA.
// LDS reads unchanged: 24 x ds_read_b128 (A 16, B 8), bank-free (8 chunks
// x 2 lanes per quarter-wave). Stage ledger per iter j (units 0=A-lo,
// 1=B-lo, 2=A-hi, 3=B-hi; 2 gloads each):
//   entry: buf c = T(j) landed; flying = T(j+1).u0.
//   P1: RD B-lo,A-lo; stage u1; 8 MFMA   P2: RD A-hi; stage u2; 8 MFMA
//   P3: RD B-hi;      stage u3; 8 MFMA;  LGKM0; SBAR
//   P4: stage T(j+2).u0 -> buf c; 8 MFMA (regs); VMW(2); SBAR
// A/B frag: lane holds row/col (l&31), k = (l>>5)*8..+7 (canonical);
// C/D (m74/m101): col = lane&31, row = (reg&3) + 8*(reg>>2) + 4*(lane>>5).
// LDS: [256 rows][128B], stored 16B-chunk = chunk ^ (row&7) (rule 21).
// ---------------------------------------------------------------------------
#define SCHED0 __builtin_amdgcn_sched_barrier(0)
#define SBAR do { SCHED0; __builtin_amdgcn_s_barrier(); SCHED0; } while (0)
#define VMW(n) asm volatile("s_waitcnt vmcnt(" #n ")" ::: "memory")
#define LGKM0 asm volatile("s_waitcnt lgkmcnt(0)" ::: "memory")
#define PRIO1 __builtin_amdgcn_s_setprio(1)
#define PRIO0 __builtin_amdgcn_s_setprio(0)

// half-tile units: 0 = A-lo, 1 = B-lo, 2 = A-hi, 3 = B-hi
#define STAGE_UNIT(bi, kt, u) do {                                          \
    const __hip_bfloat16* gsrc;  unsigned char* ldst;                       \
    if ((u) == 0)      { gsrc = A + (size_t)(m0 + r0) * HDIM;       ldst = As[bi]; }          \
    else if ((u) == 1) { gsrc = B + (size_t)(n0 + r0) * HDIM;       ldst = Bs[bi]; }          \
    else if ((u) == 2) { gsrc = A + (size_t)(m0 + 128 + r0) * HDIM; ldst = As[bi] + 16384; }  \
    else               { gsrc = B + (size_t)(n0 + 128 + r0) * HDIM; ldst = Bs[bi] + 16384; }  \
    gsrc += (size_t)(kt) * 64 + cst * 8;                                    \
    gload_lds16(gsrc, ldst + t * 16);                                       \
    gload_lds16(gsrc + (size_t)64 * HDIM, ldst + 8192 + t * 16);            \
  } while (0)

// A-frags for m-half mh (2 tiles x 4 ksteps = 8 x ds_read_b128)
#define RD_A(c, mh, dst) do { _Pragma("unroll") for (int mi = 0; mi < 2; ++mi) { \
    const int row = wm * 128 + (mh) * 64 + mi * 32 + l31;                        \
    _Pragma("unroll") for (int ks = 0; ks < 4; ++ks)                             \
      dst[mi][ks] = *(const bf16x8*)(As[c] + row * 128 + (((ks * 2 + lk) ^ rx) * 16)); \
  } } while (0)

// B-frags for n-half nh (1 tile x 4 ksteps = 4 x ds_read_b128)
#define RD_B(c, nh, dst) do {                                                    \
    const int row = wn * 64 + (nh) * 32 + l31;                                   \
    _Pragma("unroll") for (int ks = 0; ks < 4; ++ks)                             \
      dst[ks] = *(const bf16x8*)(Bs[c] + row * 128 + (((ks * 2 + lk) ^ rx) * 16)); \
  } while (0)

#define MFMA8(AF, BF, MH, NH) do { _Pragma("unroll") for (int ks = 0; ks < 4; ++ks) \
    _Pragma("unroll") for (int mi = 0; mi < 2; ++mi)                                \
      acc[(MH) * 2 + mi][NH] = __builtin_amdgcn_mfma_f32_32x32x16_bf16(             \
          AF[mi][ks], BF[ks], acc[(MH) * 2 + mi][NH], 0, 0, 0);                     \
  } while (0)

#define ITER(j, SH123, SH4, VMSTMT) do {                                     \
    const int c_ = (j) & 1, n_ = c_ ^ 1;                                     \
    /* P1: quadrant (0,0); stage T(j+1).B-lo */                              \
    RD_B(c_, 0, bfr0); RD_A(c_, 0, afr0);                                    \
    if (SH123) STAGE_UNIT(n_, (j) + 1, 1);                                   \
    SCHED0;                                                                  \
    PRIO1; MFMA8(afr0, bfr0, 0, 0); PRIO0;                                   \
    /* P2: quadrant (1,0); stage T(j+1).A-hi */                              \
    RD_A(c_, 1, afr1);                                                       \
    if (SH123) STAGE_UNIT(n_, (j) + 1, 2);                                   \
    SCHED0;                                                                  \
    PRIO1; MFMA8(afr1, bfr0, 1, 0); PRIO0;                                   \
    /* P3: quadrant (1,1); stage T(j+1).B-hi */                              \
    RD_B(c_, 1, bfr1);                                                       \
    if (SH123) STAGE_UNIT(n_, (j) + 1, 3);                                   \
    SCHED0;                                                                  \
    PRIO1; MFMA8(afr1, bfr1, 1, 1); PRIO0;                                   \
    LGKM0; SBAR;  /* all reads of buf c_ complete chip-wide */               \
    /* P4: quadrant (0,1); stage T(j+2).A-lo into freed buf c_ */            \
    if (SH4) STAGE_UNIT(c_, (j) + 2, 0);                                     \
    SCHED0;                                                                  \
    PRIO1; MFMA8(afr0, bfr1, 0, 1); PRIO0;                                   \
    VMSTMT; SBAR;                                                            \
  } while (0)

__global__ __launch_bounds__(512, 1) void gemm_bf16_kernel(
    const __hip_bfloat16* __restrict__ A,   // y_dq [8192][4096]
    const __hip_bfloat16* __restrict__ B,   // w_dq^T [4096][4096] (n-major)
    float* __restrict__ out) {              // [8192][4096]
  __shared__ __align__(16) unsigned char As[2][32768];
  __shared__ __align__(16) unsigned char Bs[2][32768];

  // XCD-aware swizzle: grid 512 = 32m x 16n tiles; XCD x gets an 8x8 sub-grid.
  const int bid = blockIdx.x;
  const int x = bid & 7, sub = bid >> 3;
  const int mtile = (x >> 1) * 8 + (sub & 7);
  const int ntile = (x & 1) * 8 + (sub >> 3);
  const int m0 = mtile * 256, n0 = ntile * 256;

  const int t = threadIdx.x;
  const int l = t & 63, wid = t >> 6;
  const int wm = wid >> 2, wn = wid & 3;    // 2x4 waves, 128x64 each
  const int l31 = l & 31, lk = l >> 5;      // 32x32 frag: row/col, k-chunk
  const int rx = l & 7;                     // row&7 for swizzled reads

  const int r0 = t >> 3;                    // staging row (0..63)
  const int cst = (t & 7) ^ (r0 & 7);       // pre-swizzled source chunk

  f32x16 acc[4][2];
#pragma unroll
  for (int a = 0; a < 4; ++a)
#pragma unroll
    for (int b = 0; b < 2; ++b)
#pragma unroll
      for (int r = 0; r < 16; ++r) acc[a][b][r] = 0.f;
  bf16x8 afr0[2][4], afr1[2][4], bfr0[4], bfr1[4];

  // prologue: T0 all 4 units -> buf0; T1.u0 -> buf1. VMW(2): T0 landed,
  // T1.u0 flying  (entry invariant of iter 0).
  STAGE_UNIT(0, 0, 0); STAGE_UNIT(0, 0, 1); STAGE_UNIT(0, 0, 2); STAGE_UNIT(0, 0, 3);
  STAGE_UNIT(1, 1, 0);
  VMW(2);
  SBAR;

  for (int j = 0; j <= NKT - 3; ++j) ITER(j, 1, 1, VMW(2));
  ITER(NKT - 2, 1, 0, VMW(0));   // drain: all of T(NKT-1) landed
  ITER(NKT - 1, 0, 0, (void)0);

  // epilogue: 32x32 C/D layout: col = l&31, row = (reg&3)+8*(reg>>2)+4*lk
#pragma unroll
  for (int mi = 0; mi < 4; ++mi)
#pragma unroll
    for (int ni = 0; ni < 2; ++ni)
#pragma unroll
      for (int reg = 0; reg < 16; ++reg) {
        const int grow = m0 + wm * 128 + mi * 32 + (reg & 3) + 8 * (reg >> 2) + 4 * lk;
        const int gcol = n0 + wn * 64 + ni * 32 + l31;
        out[(size_t)grow * HDIM + gcol] = acc[mi][ni][reg];
      }
}

// ---------------------------------------------------------------------------
extern "C" void kernel_launch(void* const* d_in, const int* in_sizes, int n_in,
                              void* d_out, int out_size, void* d_ws, size_t ws_size,
                              hipStream_t stream) {
  const float* x = (const float*)d_in[0];    // [8192][8192]
  const float* wq = (const float*)d_in[1];   // [4096][4096]
  const float* wsc = (const float*)d_in[2];  // [32][32]
  float* out = (float*)d_out;                // [8192][4096]

  unsigned short* yb = (unsigned short*)d_ws;                   // 64 MiB bf16 y_dq
  unsigned short* wt = yb + (size_t)MDIM * HDIM;                // 32 MiB bf16 w_dq^T

  silu_quant_kernel<<<MDIM, 256, 0, stream>>>(x, yb);
  wconv_kernel<<<(HDIM / 64) * (HDIM / 64), 256, 0, stream>>>(wq, wsc, wt);
  gemm_bf16_kernel<<<(MDIM / 256) * (HDIM / 256), 512, 0, stream>>>(
      (const __hip_bfloat16*)yb, (const __hip_bfloat16*)wt, out);
}

// Round 19
// 324.402 us; speedup vs baseline: 4.1654x; 1.0309x over previous
//
#include <hip/hip_runtime.h>
#include <hip/hip_fp8.h>
#include <hip/hip_bf16.h>

// Problem constants: M=8192, H=4096 (=K=N), GROUP=128.
#define MDIM 8192
#define HDIM 4096
#define NKT 64  // K tiles of 64

typedef float f32x4 __attribute__((ext_vector_type(4)));
typedef short bf16x8 __attribute__((ext_vector_type(8)));
typedef unsigned short u16x4 __attribute__((ext_vector_type(4)));

__device__ inline void gload_lds16(const void* g, void* l) {
  __builtin_amdgcn_global_load_lds(
      (const __attribute__((address_space(1))) void*)g,
      (__attribute__((address_space(3))) void*)l, 16, 0, 0);
}

__device__ inline unsigned short f2bf(float f) {
  __hip_bfloat16 h = __float2bfloat16(f);
  return *reinterpret_cast<unsigned short*>(&h);
}

// ---------------------------------------------------------------------------
// Kernel 1: y = silu(gate)*up; per-(1,128) fp8 group quant; emit y_dq as bf16.
// ---------------------------------------------------------------------------
__global__ __launch_bounds__(256) void silu_quant_kernel(
    const float* __restrict__ x, unsigned short* __restrict__ yb) {
  const int m = blockIdx.x;
  const int t = threadIdx.x;
  const int g = t >> 3;   // group 0..31
  const int i = t & 7;    // lane-in-group
  const float* xr = x + (size_t)m * (2 * HDIM);

  float v[16];
  float amax = 0.f;
#pragma unroll
  for (int j = 0; j < 4; ++j) {
    const int off = g * 128 + j * 32 + i * 4;
    f32x4 gate = *(const f32x4*)(xr + off);
    f32x4 up = *(const f32x4*)(xr + HDIM + off);
#pragma unroll
    for (int c = 0; c < 4; ++c) {
      float gg = gate[c];
      float s = gg / (1.f + expf(-gg));
      float val = s * up[c];
      v[j * 4 + c] = val;
      amax = fmaxf(amax, fabsf(val));
    }
  }
#pragma unroll
  for (int d = 1; d < 8; d <<= 1) amax = fmaxf(amax, __shfl_xor(amax, d, 64));
  const float scale = fmaxf(amax, 1e-12f) / 448.0f;

#pragma unroll
  for (int j = 0; j < 4; ++j) {
    u16x4 pk;
#pragma unroll
    for (int c = 0; c < 4; ++c) {
      __hip_fp8_e4m3 qv(v[j * 4 + c] / scale);  // RNE onto e4m3fn grid
      pk[c] = f2bf((float)qv * scale);          // dequantized, to bf16
    }
    *(u16x4*)(yb + (size_t)m * HDIM + g * 128 + j * 32 + i * 4) = pk;
  }
}

// ---------------------------------------------------------------------------
// Kernel 2: wt[n][k] = bf16( w_q[k][n] * wscale[k/128][n/128] )  (transposed)
// ---------------------------------------------------------------------------
__global__ __launch_bounds__(256) void wconv_kernel(
    const float* __restrict__ w, const float* __restrict__ wsc,
    unsigned short* __restrict__ wt) {
  __shared__ unsigned short tile[64][66];
  const int t = threadIdx.x;
  const int n0 = (blockIdx.x & 63) * 64;
  const int k0 = (blockIdx.x >> 6) * 64;
  const float ws = wsc[(k0 >> 7) * 32 + (n0 >> 7)];
  {
    const int r = t >> 4;
    const int c4 = (t & 15) << 2;
#pragma unroll
    for (int j = 0; j < 4; ++j) {
      const int kr = r + j * 16;
      f32x4 vv = *(const f32x4*)(w + (size_t)(k0 + kr) * HDIM + n0 + c4);
#pragma unroll
      for (int c = 0; c < 4; ++c) tile[kr][c4 + c] = f2bf(vv[c] * ws);
    }
  }
  __syncthreads();
  {
    const int n = t >> 4;
    const int k4 = (t & 15) << 2;
#pragma unroll
    for (int j = 0; j < 4; ++j) {
      const int nn = n + j * 16;
      u16x4 pk;
#pragma unroll
      for (int c = 0; c < 4; ++c) pk[c] = tile[k4 + c][nn];
      *(u16x4*)(wt + (size_t)(n0 + nn) * HDIM + k0 + k4) = pk;
    }
  }
}

// ---------------------------------------------------------------------------
// Kernel 3: bf16 GEMM, 256x256 tile, BK=64, 8 waves (2Mx4N, 128x64 each),
// 16x16x32 MFMA (r18's 32x32 had 25M bank conflicts -> reverted).
// m201-faithful 8-phase / 2-K-tile schedule, counted vmcnt(6) (T3+T4):
// tile j lives in buf j&1. Per iter (tiles kt2, kt2+1), phase skeleton
// {ds-read subtile; stage 1 unit; SBAR; LGKM0; prio1 16xMFMA prio0; SBAR},
// vmcnt(6) only at phases 4 and 8 (never 0 in main loop; 3 units in flight).
// STAGE SCHEDULE (unit u: 0=A-lo,1=B-lo,2=A-hi,3=B-hi; 2 gloads each):
//   p1: B-hi(kt2+1)->buf1   [occupant B-hi(kt2-1) last read p7 prev iter]
//   p2: A-lo(kt2+2)->buf0   [A-lo(kt2) last read p1]
//   p3: B-lo(kt2+2)->buf0   [B-lo(kt2) last read p1]
//   p4: A-hi(kt2+2)->buf0   [A-hi(kt2) last read p2]; VMW(6)
//   p5: B-hi(kt2+2)->buf0   [B-hi(kt2) last read p3]
//   p6: A-lo(kt2+3)->buf1   [A-lo(kt2+1) last read p5]
//   p7: B-lo(kt2+3)->buf1   [B-lo(kt2+1) last read p5]
//   p8: A-hi(kt2+3)->buf1   [A-hi(kt2+1) last read p6]; VMW(6)
// VMW(6) ledger (steady state): at p4, outstanding = {A-lo,B-lo,A-hi(kt2+1)
// from prev p6-8} + {p1..p4 stages} = 14 loads; wait->6 confirms the 4
// oldest units = ALL of tile kt2+1 (read p5-8). At p8: confirms all of
// tile kt2+2 (read next iter p1-4). Every write target freed by the
// trailing barrier of the phase where its occupant was last read (each
// wave LGKM0s before its MFMA, barrier joins all waves).
// LDS: [256 rows][128B], stored 16B-chunk = chunk ^ (row&7); linear dest +
// pre-swizzled global source + swizzled ds_read (rule 21). Conflict-free
// (r6/r8/r10/r11: SQ_LDS_BANK_CONFLICT = 0 with this exact read pattern).
// ---------------------------------------------------------------------------
#define SCHED0 __builtin_amdgcn_sched_barrier(0)
#define SBAR do { SCHED0; __builtin_amdgcn_s_barrier(); SCHED0; } while (0)
#define VMW(n) asm volatile("s_waitcnt vmcnt(" #n ")" ::: "memory")
#define LGKM0 asm volatile("s_waitcnt lgkmcnt(0)" ::: "memory")
#define PRIO1 __builtin_amdgcn_s_setprio(1)
#define PRIO0 __builtin_amdgcn_s_setprio(0)

#define STAGE_UNIT(bi, kt, u) do {                                          \
    const __hip_bfloat16* gsrc;  unsigned char* ldst;                       \
    if ((u) == 0)      { gsrc = A + (size_t)(m0 + r0) * HDIM;       ldst = As[bi]; }          \
    else if ((u) == 1) { gsrc = B + (size_t)(n0 + r0) * HDIM;       ldst = Bs[bi]; }          \
    else if ((u) == 2) { gsrc = A + (size_t)(m0 + 128 + r0) * HDIM; ldst = As[bi] + 16384; }  \
    else               { gsrc = B + (size_t)(n0 + 128 + r0) * HDIM; ldst = Bs[bi] + 16384; }  \
    gsrc += (size_t)(kt) * 64 + cst * 8;                                    \
    gload_lds16(gsrc, ldst + t * 16);                                       \
    gload_lds16(gsrc + (size_t)64 * HDIM, ldst + 8192 + t * 16);            \
  } while (0)

#define RD_A(c, mh, dst) do { _Pragma("unroll") for (int mi = 0; mi < 4; ++mi) { \
    const int row = wm * 128 + (mh) * 64 + mi * 16 + lrow;                       \
    _Pragma("unroll") for (int kk = 0; kk < 2; ++kk)                             \
      dst[mi][kk] = *(const bf16x8*)(As[c] + row * 128 + (((kk * 4 + lhi) ^ rx) * 16)); \
  } } while (0)

#define RD_B(c, nh, dst) do { _Pragma("unroll") for (int ni = 0; ni < 2; ++ni) { \
    const int row = wn * 64 + (nh) * 32 + ni * 16 + lrow;                        \
    _Pragma("unroll") for (int kk = 0; kk < 2; ++kk)                             \
      dst[ni][kk] = *(const bf16x8*)(Bs[c] + row * 128 + (((kk * 4 + lhi) ^ rx) * 16)); \
  } } while (0)

#define MFMA16(AF, BF, MB, NB) do { _Pragma("unroll") for (int kk = 0; kk < 2; ++kk) \
    _Pragma("unroll") for (int mi = 0; mi < 4; ++mi)                                 \
      _Pragma("unroll") for (int ni = 0; ni < 2; ++ni)                               \
        acc[(MB) + mi][(NB) + ni] = __builtin_amdgcn_mfma_f32_16x16x32_bf16(         \
            AF[mi][kk], BF[ni][kk], acc[(MB) + mi][(NB) + ni], 0, 0, 0);             \
  } while (0)

// One unrolled iter = tiles kt2 (buf0) and kt2+1 (buf1), 8 phases.
#define ITER2(kt2, SHM, VM4, VM8) do {                                       \
    /* p1: tile kt2 q(0,0); stage B-hi(kt2+1) */                             \
    RD_A(0, 0, afr0); RD_B(0, 0, bfr0);                                      \
    STAGE_UNIT(1, (kt2) + 1, 3);                                             \
    SBAR; LGKM0; SCHED0;                                                     \
    PRIO1; MFMA16(afr0, bfr0, 0, 0); PRIO0;                                  \
    SBAR;                                                                    \
    /* p2: q(1,0); stage A-lo(kt2+2) */                                      \
    RD_A(0, 1, afr1);                                                        \
    if (SHM) STAGE_UNIT(0, (kt2) + 2, 0);                                    \
    SBAR; LGKM0; SCHED0;                                                     \
    PRIO1; MFMA16(afr1, bfr0, 4, 0); PRIO0;                                  \
    SBAR;                                                                    \
    /* p3: q(1,1); stage B-lo(kt2+2) */                                      \
    RD_B(0, 1, bfr1);                                                        \
    if (SHM) STAGE_UNIT(0, (kt2) + 2, 1);                                    \
    SBAR; LGKM0; SCHED0;                                                     \
    PRIO1; MFMA16(afr1, bfr1, 4, 2); PRIO0;                                  \
    SBAR;                                                                    \
    /* p4: q(0,1) from regs; stage A-hi(kt2+2); counted confirm of kt2+1 */  \
    if (SHM) STAGE_UNIT(0, (kt2) + 2, 2);                                    \
    SBAR;                                                                    \
    PRIO1; MFMA16(afr0, bfr1, 0, 2); PRIO0;                                  \
    VM4; SBAR;                                                               \
    /* p5: tile kt2+1 q(0,0); stage B-hi(kt2+2) */                           \
    RD_A(1, 0, afr0); RD_B(1, 0, bfr0);                                      \
    if (SHM) STAGE_UNIT(0, (kt2) + 2, 3);                                    \
    SBAR; LGKM0; SCHED0;                                                     \
    PRIO1; MFMA16(afr0, bfr0, 0, 0); PRIO0;                                  \
    SBAR;                                                                    \
    /* p6: q(1,0); stage A-lo(kt2+3) */                                      \
    RD_A(1, 1, afr1);                                                        \
    if (SHM) STAGE_UNIT(1, (kt2) + 3, 0);                                    \
    SBAR; LGKM0; SCHED0;                                                     \
    PRIO1; MFMA16(afr1, bfr0, 4, 0); PRIO0;                                  \
    SBAR;                                                                    \
    /* p7: q(1,1); stage B-lo(kt2+3) */                                      \
    RD_B(1, 1, bfr1);                                                        \
    if (SHM) STAGE_UNIT(1, (kt2) + 3, 1);                                    \
    SBAR; LGKM0; SCHED0;                                                     \
    PRIO1; MFMA16(afr1, bfr1, 4, 2); PRIO0;                                  \
    SBAR;                                                                    \
    /* p8: q(0,1); stage A-hi(kt2+3); counted confirm of kt2+2 */            \
    if (SHM) STAGE_UNIT(1, (kt2) + 3, 2);                                    \
    SBAR;                                                                    \
    PRIO1; MFMA16(afr0, bfr1, 0, 2); PRIO0;                                  \
    VM8; SBAR;                                                               \
  } while (0)

__global__ __launch_bounds__(512, 1) void gemm_bf16_kernel(
    const __hip_bfloat16* __restrict__ A,   // y_dq [8192][4096]
    const __hip_bfloat16* __restrict__ B,   // w_dq^T [4096][4096] (n-major)
    float* __restrict__ out) {              // [8192][4096]
  __shared__ __align__(16) unsigned char As[2][32768];
  __shared__ __align__(16) unsigned char Bs[2][32768];

  // XCD-aware swizzle: grid 512 = 32m x 16n tiles; XCD x gets an 8x8 sub-grid.
  const int bid = blockIdx.x;
  const int x = bid & 7, sub = bid >> 3;
  const int mtile = (x >> 1) * 8 + (sub & 7);
  const int ntile = (x & 1) * 8 + (sub >> 3);
  const int m0 = mtile * 256, n0 = ntile * 256;

  const int t = threadIdx.x;
  const int l = t & 63, wid = t >> 6;
  const int wm = wid >> 2, wn = wid & 3;    // 2x4 waves, 128x64 each
  const int lrow = l & 15, lhi = l >> 4;
  const int rx = lrow & 7;

  const int r0 = t >> 3;                    // staging row (0..63)
  const int cst = (t & 7) ^ (r0 & 7);       // pre-swizzled source chunk

  f32x4 acc[8][4];
#pragma unroll
  for (int a = 0; a < 8; ++a)
#pragma unroll
    for (int b = 0; b < 4; ++b) acc[a][b] = (f32x4){0.f, 0.f, 0.f, 0.f};
  bf16x8 afr0[4][2], afr1[4][2], bfr0[2][2], bfr1[2][2];

  // prologue: tile0 fully -> buf0; A-lo,B-lo,A-hi(1) -> buf1 (7 units).
  // VMW(6) confirms tile0's 8 loads; 3 units of tile1 stay in flight
  // (steady-state entry invariant: p1 will stage B-hi(1), p4 confirms tile1).
  STAGE_UNIT(0, 0, 0); STAGE_UNIT(0, 0, 1); STAGE_UNIT(0, 0, 2); STAGE_UNIT(0, 0, 3);
  STAGE_UNIT(1, 1, 0); STAGE_UNIT(1, 1, 1); STAGE_UNIT(1, 1, 2);
  VMW(6);
  SBAR;

  for (int kt2 = 0; kt2 < NKT - 2; kt2 += 2) ITER2(kt2, 1, VMW(6), VMW(6));
  // last pair (tiles 62,63): p1 stages B-hi(63) (pipeline tail), no other
  // stages; p4's VMW(0) drains the remaining 8 loads = all of tile 63.
  ITER2(NKT - 2, 0, VMW(0), (void)0);

  // epilogue: C row = lhi*4+r (m), col = lrow (n)
#pragma unroll
  for (int mi = 0; mi < 8; ++mi)
#pragma unroll
    for (int r = 0; r < 4; ++r) {
      const int grow = m0 + wm * 128 + mi * 16 + lhi * 4 + r;
      float* orow = out + (size_t)grow * HDIM + n0 + wn * 64 + lrow;
#pragma unroll
      for (int ni = 0; ni < 4; ++ni) orow[ni * 16] = acc[mi][ni][r];
    }
}

// ---------------------------------------------------------------------------
extern "C" void kernel_launch(void* const* d_in, const int* in_sizes, int n_in,
                              void* d_out, int out_size, void* d_ws, size_t ws_size,
                              hipStream_t stream) {
  const float* x = (const float*)d_in[0];    // [8192][8192]
  const float* wq = (const float*)d_in[1];   // [4096][4096]
  const float* wsc = (const float*)d_in[2];  // [32][32]
  float* out = (float*)d_out;                // [8192][4096]

  unsigned short* yb = (unsigned short*)d_ws;                   // 64 MiB bf16 y_dq
  unsigned short* wt = yb + (size_t)MDIM * HDIM;                // 32 MiB bf16 w_dq^T

  silu_quant_kernel<<<MDIM, 256, 0, stream>>>(x, yb);
  wconv_kernel<<<(HDIM / 64) * (HDIM / 64), 256, 0, stream>>>(wq, wsc, wt);
  gemm_bf16_kernel<<<(MDIM / 256) * (HDIM / 256), 512, 0, stream>>>(
      (const __hip_bfloat16*)yb, (const __hip_bfloat16*)wt, out);
}